// Round 6
// baseline (165.903 us; speedup 1.0000x reference)
//
#include <hip/hip_runtime.h>
#include <math.h>

// out = softmax((Q .* K^T) / 64 .* V, axis=1)   (elementwise, NOT matmul)
// Q: [8192,4096] f32; K: [4096,8192] f32 (need K[j][i]); V,O: [8192,4096].
//
// One block = 16 rows, one wave per row (1024 thr). Row payload in 16 NAMED
// float4 regs (array form spilled: R1/R2). No max-subtract: |x| <= ~1.5.
//
// R5/R6: latency-bound fix (Little's law). R4 measured 8.5 GB/s/CU vs 24.6
// needed; ~6 KB/wave bursty in flight. Changes: (1) TJ=512 (8 tiles) -> 2x
// bytes per issue burst, half the barriers; (2) issue next-tile loads FIRST
// in the tile body (before the vmcnt-waited ds_write) so they stay in
// flight a full period; (3) launch_bounds(1024,8) caps regs at 256 ->
// 2 blocks/CU resident, decorrelated barriers. LDS barrier (lgkmcnt only,
// no vmcnt drain) kept from R4.  (R6 = R5 with the pp-token paste fixed:
// (q##QC##0).x instead of q##QC##0.x.)

static constexpr int NROW = 8192;
static constexpr int D    = 4096;
static constexpr int RPB  = 16;          // rows per block == waves per block
static constexpr int TJ   = 512;         // columns per tile
static constexpr int NT   = D / TJ;      // 8 tiles
static constexpr int LSTR = TJ + 4;      // 516 floats: pad spreads banks

#define LDS_BARRIER() asm volatile("s_waitcnt lgkmcnt(0)\n\ts_barrier" ::: "memory")

__global__ __launch_bounds__(1024, 8)    // cap 256 regs -> 2 blocks/CU
void sdp_softmax_kernel(const float* __restrict__ Q,
                        const float* __restrict__ K,
                        const float* __restrict__ V,
                        float* __restrict__ O)
{
    __shared__ float ldsK[2][RPB * LSTR];

    const int tid  = threadIdx.x;
    const int wv   = tid >> 6;           // wave id = local row
    const int lane = tid & 63;

    // XCD-chunked swizzle (512 % 8 == 0, bijective): adjacent row-blocks on
    // one XCD share K 128B lines (R4: FETCH 256 -> 192 MiB).
    const int nwg = gridDim.x;
    const int cpx = nwg >> 3;
    const int hb  = blockIdx.x;
    const int lb  = (hb & 7) * cpx + (hb >> 3);

    const int row0 = lb * RPB;
    const int r    = row0 + wv;

    const float* qrow = Q + (size_t)r * D;
    const float* vrow = V + (size_t)r * D;
    float*       orow = O + (size_t)r * D;

    // K staging: thread t loads 8 consecutive j (rows of K), fixed i=row0+il.
    // Per instr: 4 jg-groups x 16 contiguous lanes = 4 full 64B segments.
    const int il = tid & 15;
    const int jg = tid >> 4;             // 0..63 -> j base 8*jg
    const float* kbase = K + (size_t)(8 * jg) * NROW + (size_t)row0 + il;
    const float scl = 0.015625f;         // 1/64 exact

    // ---- prologue: stage K tile 0 -> buf0; issue K(1)->kA, Q/V(0)->A ----
    {
        float t0 = kbase[0];
        float t1 = kbase[NROW];
        float t2 = kbase[2 * (size_t)NROW];
        float t3 = kbase[3 * (size_t)NROW];
        float t4 = kbase[4 * (size_t)NROW];
        float t5 = kbase[5 * (size_t)NROW];
        float t6 = kbase[6 * (size_t)NROW];
        float t7 = kbase[7 * (size_t)NROW];
        *(float4*)&ldsK[0][il * LSTR + 8 * jg]     = make_float4(t0, t1, t2, t3);
        *(float4*)&ldsK[0][il * LSTR + 8 * jg + 4] = make_float4(t4, t5, t6, t7);
    }
    float kA0, kA1, kA2, kA3, kA4, kA5, kA6, kA7;
    float kB0, kB1, kB2, kB3, kB4, kB5, kB6, kB7;
    {
        const float* p = kbase + (size_t)TJ * NROW;
        kA0 = p[0];                  kA1 = p[NROW];
        kA2 = p[2 * (size_t)NROW];   kA3 = p[3 * (size_t)NROW];
        kA4 = p[4 * (size_t)NROW];   kA5 = p[5 * (size_t)NROW];
        kA6 = p[6 * (size_t)NROW];   kA7 = p[7 * (size_t)NROW];
    }
    float4 qA0 = *(const float4*)(qrow + 4 * lane);
    float4 qA1 = *(const float4*)(qrow + 256 + 4 * lane);
    float4 vA0 = *(const float4*)(vrow + 4 * lane);
    float4 vA1 = *(const float4*)(vrow + 256 + 4 * lane);
    float4 qB0, qB1, vB0, vB1;
    LDS_BARRIER();

    float4 e0, e1, e2, e3, e4, e5, e6, e7,
           e8, e9, e10, e11, e12, e13, e14, e15;
    float s = 0.0f;

    // Iter n entry: buf[n&1] = K tile n; KW regs = K(n+1); QC/VC = Q/V(n).
    // Body order: (a) ISSUE K(n+2)->KL, Q/V(n+1)->QN  [stay in flight ~1
    // period]; (b) ds_read kf; (c) ds_write KW; (d) exp+sum; (e) LDS
    // barrier (no vmcnt drain).
#define TILE_ITER(n, EVa, EVb, KW, KL, QC, QN)                                \
    {                                                                         \
        if ((n) + 2 < NT) {                                                   \
            const float* p = kbase + (size_t)((n) + 2) * TJ * NROW;           \
            KL##0 = p[0];                KL##1 = p[NROW];                     \
            KL##2 = p[2 * (size_t)NROW]; KL##3 = p[3 * (size_t)NROW];         \
            KL##4 = p[4 * (size_t)NROW]; KL##5 = p[5 * (size_t)NROW];         \
            KL##6 = p[6 * (size_t)NROW]; KL##7 = p[7 * (size_t)NROW];         \
        }                                                                     \
        if ((n) + 1 < NT) {                                                   \
            q##QN##0 = *(const float4*)(qrow + ((n)+1)*TJ + 4*lane);          \
            q##QN##1 = *(const float4*)(qrow + ((n)+1)*TJ + 256 + 4*lane);    \
            v##QN##0 = *(const float4*)(vrow + ((n)+1)*TJ + 4*lane);          \
            v##QN##1 = *(const float4*)(vrow + ((n)+1)*TJ + 256 + 4*lane);    \
        }                                                                     \
        const float4 kf0 = *(const float4*)&ldsK[(n)&1][wv*LSTR + 4*lane];    \
        const float4 kf1 = *(const float4*)&ldsK[(n)&1][wv*LSTR + 256 + 4*lane];\
        if ((n) + 1 < NT) {                                                   \
            *(float4*)&ldsK[((n)+1)&1][il*LSTR + 8*jg] =                      \
                make_float4(KW##0, KW##1, KW##2, KW##3);                      \
            *(float4*)&ldsK[((n)+1)&1][il*LSTR + 8*jg + 4] =                  \
                make_float4(KW##4, KW##5, KW##6, KW##7);                      \
        }                                                                     \
        EVa.x = __expf((((q##QC##0).x * kf0.x) * scl) * (v##QC##0).x);        \
        EVa.y = __expf((((q##QC##0).y * kf0.y) * scl) * (v##QC##0).y);        \
        EVa.z = __expf((((q##QC##0).z * kf0.z) * scl) * (v##QC##0).z);        \
        EVa.w = __expf((((q##QC##0).w * kf0.w) * scl) * (v##QC##0).w);        \
        EVb.x = __expf((((q##QC##1).x * kf1.x) * scl) * (v##QC##1).x);        \
        EVb.y = __expf((((q##QC##1).y * kf1.y) * scl) * (v##QC##1).y);        \
        EVb.z = __expf((((q##QC##1).z * kf1.z) * scl) * (v##QC##1).z);        \
        EVb.w = __expf((((q##QC##1).w * kf1.w) * scl) * (v##QC##1).w);        \
        s += ((EVa.x + EVa.y) + (EVa.z + EVa.w)) +                            \
             ((EVb.x + EVb.y) + (EVb.z + EVb.w));                             \
        if ((n) + 1 < NT) LDS_BARRIER();                                      \
        __builtin_amdgcn_sched_barrier(0);                                    \
    }

    TILE_ITER(0, e0,  e1,  kA, kB, A, B)
    TILE_ITER(1, e2,  e3,  kB, kA, B, A)
    TILE_ITER(2, e4,  e5,  kA, kB, A, B)
    TILE_ITER(3, e6,  e7,  kB, kA, B, A)
    TILE_ITER(4, e8,  e9,  kA, kB, A, B)
    TILE_ITER(5, e10, e11, kB, kA, B, A)
    TILE_ITER(6, e12, e13, kA, kB, A, B)
    TILE_ITER(7, e14, e15, kB, kA, B, A)
#undef TILE_ITER

    // row sum (row == wave): butterfly across 64 lanes
    #pragma unroll
    for (int i = 1; i < 64; i <<= 1)
        s += __shfl_xor(s, i, 64);
    const float inv = 1.0f / s;

#define WRITE_TILE(c, EV)                                                     \
    {                                                                         \
        float4 xx = EV;                                                       \
        xx.x *= inv; xx.y *= inv; xx.z *= inv; xx.w *= inv;                   \
        *(float4*)(orow + (size_t)(c) * 256 + 4 * lane) = xx;                 \
    }

    WRITE_TILE(0,  e0)  WRITE_TILE(1,  e1)  WRITE_TILE(2,  e2)  WRITE_TILE(3,  e3)
    WRITE_TILE(4,  e4)  WRITE_TILE(5,  e5)  WRITE_TILE(6,  e6)  WRITE_TILE(7,  e7)
    WRITE_TILE(8,  e8)  WRITE_TILE(9,  e9)  WRITE_TILE(10, e10) WRITE_TILE(11, e11)
    WRITE_TILE(12, e12) WRITE_TILE(13, e13) WRITE_TILE(14, e14) WRITE_TILE(15, e15)
#undef WRITE_TILE
}

extern "C" void kernel_launch(void* const* d_in, const int* in_sizes, int n_in,
                              void* d_out, int out_size, void* d_ws, size_t ws_size,
                              hipStream_t stream) {
    const float* Q = (const float*)d_in[0];
    const float* K = (const float*)d_in[1];
    const float* V = (const float*)d_in[2];
    float* O = (float*)d_out;

    dim3 grid(NROW / RPB);   // 512 blocks
    dim3 block(1024);        // 16 waves
    sdp_softmax_kernel<<<grid, block, 0, stream>>>(Q, K, V, O);
}

// Round 7
// 121.335 us; speedup vs baseline: 1.3673x; 1.3673x over previous
//
#include <hip/hip_runtime.h>
#include <math.h>

// out = softmax((Q .* K^T) / 64 .* V, axis=1)   (elementwise, NOT matmul)
// Q: [8192,4096] f32; K: [4096,8192] f32 (need K[j][i]); V,O: [8192,4096].
//
// R7 structure: block = 8 rows (8 waves, 512 thr). The ENTIRE K band for the
// block's 8 rows is transposed into LDS once (8 x 4100 floats = 128.1 KiB,
// <= 160 KiB; m201 precedent for >64KB static LDS on gfx950), then ONE
// barrier, then each wave streams its row with deep prefetch and NO barriers
// at all (R4's per-tile barrier lockstep made tile period ~ loaded latency:
// 3.7 us/tile vs 1.95 us fair-share-BW time). Payload in 16 NAMED float4
// (array form spilled: R1/R2). launch_bounds(512,2): min-waves arg LOW so
// the allocator is NOT forced to spill (R6 lesson: (1024,8) caps VGPR=64).
// No max-subtract: x = q*k*v/64, |x| <~ 1.5 (std 1/64), exp safe in f32.

static constexpr int NROW = 8192;
static constexpr int D    = 4096;
static constexpr int RPB  = 8;           // rows per block == waves per block
static constexpr int LSTR = D + 4;       // 4100: odd-granule stride, banks spread
static constexpr int NT   = 16;          // col tiles of 256

#define LDS_BARRIER() asm volatile("s_waitcnt lgkmcnt(0)\n\ts_barrier" ::: "memory")

__global__ __launch_bounds__(512, 2)
void sdp_softmax_kernel(const float* __restrict__ Q,
                        const float* __restrict__ K,
                        const float* __restrict__ V,
                        float* __restrict__ O)
{
    __shared__ float ldsK[RPB * LSTR];   // 131,200 B

    const int tid  = threadIdx.x;
    const int wv   = tid >> 6;           // wave id = local row (0..7)
    const int lane = tid & 63;

    // XCD-chunked swizzle (1024 % 8 == 0, bijective): rows of one XCD are
    // contiguous -> K's 128B L2 lines shared by 4 adjacent row-blocks.
    const int nwg = gridDim.x;           // 1024
    const int cpx = nwg >> 3;            // 128
    const int hb  = blockIdx.x;
    const int lb  = (hb & 7) * cpx + (hb >> 3);

    const int row0 = lb * RPB;
    const int r    = row0 + wv;

    const float* qrow = Q + (size_t)r * D;
    const float* vrow = V + (size_t)r * D;
    float*       orow = O + (size_t)r * D;

    // K staging: thread (il = tid&7, jg = tid>>3) gathers K[j][row0+il] for
    // j = 512*b + 8*jg + m, m=0..7, batches b=0..7.  Per load instr: 8
    // contiguous il lanes = 32B segments (L2 line completes via neighbor
    // blocks on same XCD).  64 independent dword loads/thread, 2-deep batch
    // pipeline -> staging is BW-bound, not latency-bound.
    const int il = tid & 7;
    const int jg = tid >> 3;             // 0..63
    const float* kbase = K + (size_t)(8 * jg) * NROW + (size_t)row0 + il;
    const float scl = 0.015625f;         // 1/64 exact

    float sa0, sa1, sa2, sa3, sa4, sa5, sa6, sa7;
    float sb0, sb1, sb2, sb3, sb4, sb5, sb6, sb7;

#define LOADB(R, b)                                                           \
    {                                                                         \
        const float* p = kbase + (size_t)(512 * (b)) * NROW;                  \
        R##0 = p[0];                  R##1 = p[NROW];                         \
        R##2 = p[2 * (size_t)NROW];   R##3 = p[3 * (size_t)NROW];             \
        R##4 = p[4 * (size_t)NROW];   R##5 = p[5 * (size_t)NROW];             \
        R##6 = p[6 * (size_t)NROW];   R##7 = p[7 * (size_t)NROW];             \
    }
#define WRITEB(R, b)                                                          \
    {                                                                         \
        float* w = &ldsK[il * LSTR + 512 * (b) + 8 * jg];                     \
        *(float4*)w       = make_float4(R##0, R##1, R##2, R##3);              \
        *(float4*)(w + 4) = make_float4(R##4, R##5, R##6, R##7);              \
    }

    LOADB(sa, 0)
    // Q/V prologue for tiles 0..3 issued early: in flight during staging+barrier.
    float4 qS0 = *(const float4*)(qrow + 0 * 256 + 4 * lane);
    float4 vS0 = *(const float4*)(vrow + 0 * 256 + 4 * lane);
    float4 qS1 = *(const float4*)(qrow + 1 * 256 + 4 * lane);
    float4 vS1 = *(const float4*)(vrow + 1 * 256 + 4 * lane);
    float4 qS2 = *(const float4*)(qrow + 2 * 256 + 4 * lane);
    float4 vS2 = *(const float4*)(vrow + 2 * 256 + 4 * lane);
    float4 qS3 = *(const float4*)(qrow + 3 * 256 + 4 * lane);
    float4 vS3 = *(const float4*)(vrow + 3 * 256 + 4 * lane);

    LOADB(sb, 1) WRITEB(sa, 0)
    LOADB(sa, 2) WRITEB(sb, 1)
    LOADB(sb, 3) WRITEB(sa, 2)
    LOADB(sa, 4) WRITEB(sb, 3)
    LOADB(sb, 5) WRITEB(sa, 4)
    LOADB(sa, 6) WRITEB(sb, 5)
    LOADB(sb, 7) WRITEB(sa, 6)
    WRITEB(sb, 7)
#undef LOADB
#undef WRITEB

    LDS_BARRIER();   // the ONLY barrier; Q/V loads stay in flight across it

    float4 kfA = *(const float4*)&ldsK[wv * LSTR + 4 * lane];   // kf tile 0
    float4 kfB;
    float4 e0, e1, e2, e3, e4, e5, e6, e7,
           e8, e9, e10, e11, e12, e13, e14, e15;
    float s = 0.0f;

    // Body t: prefetch kf(t+1) from LDS; consume q/v slot (t&3) then refill
    // it with tile t+4 (6-8 float4 outstanding/wave; counted vmcnt, never 0;
    // no barriers anywhere in this loop).
#define BODY(t, ET, KC, KN, QS, VS)                                           \
    {                                                                         \
        if ((t) + 1 < NT)                                                     \
            KN = *(const float4*)&ldsK[wv * LSTR + ((t) + 1) * 256 + 4*lane]; \
        const float4 qc = QS, vc = VS;                                        \
        if ((t) + 4 < NT) {                                                   \
            QS = *(const float4*)(qrow + ((t) + 4) * 256 + 4 * lane);         \
            VS = *(const float4*)(vrow + ((t) + 4) * 256 + 4 * lane);         \
        }                                                                     \
        ET.x = __expf(((qc.x * (KC).x) * scl) * vc.x);                        \
        ET.y = __expf(((qc.y * (KC).y) * scl) * vc.y);                        \
        ET.z = __expf(((qc.z * (KC).z) * scl) * vc.z);                        \
        ET.w = __expf(((qc.w * (KC).w) * scl) * vc.w);                        \
        s += ((ET.x + ET.y) + (ET.z + ET.w));                                 \
        __builtin_amdgcn_sched_barrier(0);                                    \
    }

    BODY(0,  e0,  kfA, kfB, qS0, vS0)
    BODY(1,  e1,  kfB, kfA, qS1, vS1)
    BODY(2,  e2,  kfA, kfB, qS2, vS2)
    BODY(3,  e3,  kfB, kfA, qS3, vS3)
    BODY(4,  e4,  kfA, kfB, qS0, vS0)
    BODY(5,  e5,  kfB, kfA, qS1, vS1)
    BODY(6,  e6,  kfA, kfB, qS2, vS2)
    BODY(7,  e7,  kfB, kfA, qS3, vS3)
    BODY(8,  e8,  kfA, kfB, qS0, vS0)
    BODY(9,  e9,  kfB, kfA, qS1, vS1)
    BODY(10, e10, kfA, kfB, qS2, vS2)
    BODY(11, e11, kfB, kfA, qS3, vS3)
    BODY(12, e12, kfA, kfB, qS0, vS0)
    BODY(13, e13, kfB, kfA, qS1, vS1)
    BODY(14, e14, kfA, kfB, qS2, vS2)
    BODY(15, e15, kfB, kfA, qS3, vS3)
#undef BODY

    // row sum (row == wave, no cross-wave): butterfly across 64 lanes
    #pragma unroll
    for (int i = 1; i < 64; i <<= 1)
        s += __shfl_xor(s, i, 64);
    const float inv = 1.0f / s;

#define WRITE_TILE(t, ET)                                                     \
    {                                                                         \
        float4 xx = ET;                                                       \
        xx.x *= inv; xx.y *= inv; xx.z *= inv; xx.w *= inv;                   \
        *(float4*)(orow + (size_t)(t) * 256 + 4 * lane) = xx;                 \
    }

    WRITE_TILE(0,  e0)  WRITE_TILE(1,  e1)  WRITE_TILE(2,  e2)  WRITE_TILE(3,  e3)
    WRITE_TILE(4,  e4)  WRITE_TILE(5,  e5)  WRITE_TILE(6,  e6)  WRITE_TILE(7,  e7)
    WRITE_TILE(8,  e8)  WRITE_TILE(9,  e9)  WRITE_TILE(10, e10) WRITE_TILE(11, e11)
    WRITE_TILE(12, e12) WRITE_TILE(13, e13) WRITE_TILE(14, e14) WRITE_TILE(15, e15)
#undef WRITE_TILE
}

extern "C" void kernel_launch(void* const* d_in, const int* in_sizes, int n_in,
                              void* d_out, int out_size, void* d_ws, size_t ws_size,
                              hipStream_t stream) {
    const float* Q = (const float*)d_in[0];
    const float* K = (const float*)d_in[1];
    const float* V = (const float*)d_in[2];
    float* O = (float*)d_out;

    dim3 grid(NROW / RPB);   // 1024 blocks
    dim3 block(512);         // 8 waves
    sdp_softmax_kernel<<<grid, block, 0, stream>>>(Q, K, V, O);
}